// Round 3
// baseline (2083.093 us; speedup 1.0000x reference)
//
#include <hip/hip_runtime.h>

// Residual quantizer: N=65536 vectors (D=128), M=8 stages, K=256 codewords.
//
// R4->R5: R4 was still latency-bound at 2 waves/SIMD (VALUBusy 53%, dur ~3x
// the max(VALU,LDS) floor, conflicts 0, no spills). More occupancy normally
// costs LDS reuse (traffic = threads x codewords/thread x 64B). Escape: K-SPLIT.
// Keep 4 vectors per 8-lane group (reuse unchanged: 16B LDS read feeds 64
// FMAs), but each thread scans only HALF the codebook: 512-thread blocks,
// tid<256 -> k in [0,128), tid>=256 -> k in [128,256), same 128 vectors.
// Threads double to 262144 (512 blocks, 2 blocks/CU at 72KB LDS -> 16
// waves/CU = 4 waves/SIMD) while total LDS traffic and VALU work are exactly
// unchanged. Halves merge argmin through (reused) sC; stores split: half0
// writes side+recon, half1 writes codes. Chunks pair sub-ranges (56+56,
// 56+56, 16+16 rows) so both halves work every chunk; CST=20 layout kept.
//
// Numerics (absmax must stay 0.0): every FP sequence is byte-for-byte R4's.
// Chain c (mul + 15 sequential fma over elements 8k+c) whole in lane c&7.
// Combine: dpp quad xor1 (0xB1), xor2 (0x4E), half mirror (0x141) replicates
// ((p0+p1)+(p2+p3))+((p4+p5)+(p6+p7)) bitwise in all 8 lanes. dist =
// (rn - 2*dot) + cn, strict <. Merge rule: (hi < lo) ? hi : lo keeps
// first-min-wins (half0 indices smaller; ties pick lo). Both halves
// redundantly maintain rec/res (identical bits). rec += c; res = x - rec.

constexpr int NV = 65536;
constexpr int DD = 128;
constexpr int MS = 8;
constexpr int KC = 256;
constexpr int CH = 112;       // LDS row slots per chunk (56+56 or 16+16)
constexpr int CST = 20;       // chain stride in dwords (16B-aligned, conflict-free)
constexpr int RST = 8 * CST;  // row stride in dwords = 160 (640 B)

// paired chunk tables: half0 rows [CB0, CB0+CNT), half1 rows [CB1, CB1+CNT)
constexpr int CB0[3]  = {0, 56, 112};
constexpr int CB1[3]  = {128, 184, 240};
constexpr int CCNT[3] = {56, 56, 16};

template<int CTRL>
__device__ __forceinline__ float bfly_add(float v) {
    // v + dpp<CTRL>(v); 0xB1 = quad xor1, 0x4E = quad xor2, 0x141 = row_half_mirror
    int p = __builtin_amdgcn_update_dpp(__float_as_int(v), __float_as_int(v),
                                        CTRL, 0xF, 0xF, true);
    return v + __int_as_float(p);
}

__global__ __launch_bounds__(512, 4)
void rq_kernel(const float* __restrict__ x,
               const float* __restrict__ cb,
               float* __restrict__ out)
{
    const int tid = threadIdx.x;
    const int h   = tid >> 8;                 // codebook half (wave-uniform)
    const int c   = tid & 7;                  // chain owned (elements 8k+c)
    const int grp = (tid >> 3) & 31;          // vector group (0..31)
    const size_t vbase = (size_t)blockIdx.x * 128 + (size_t)grp * 4;

    __shared__ __align__(16) float sC[CH * RST];   // 71680 B, chain-major+pad
    __shared__ float cn_s[CH];                     // 448 B

    // Per-lane state: chain c of 4 vectors. rA = res, cA = rec.
    float rA[4][16], cA[4][16];

    #pragma unroll
    for (int v = 0; v < 4; ++v) {
        const float* xr = x + (vbase + v) * DD + c;
        #pragma unroll
        for (int k = 0; k < 16; ++k) {
            rA[v][k] = xr[8 * k];
            cA[v][k] = 0.0f;
        }
    }

    float* out_recon = out;                                  // (N, D)
    float* out_codes = out + (size_t)NV * DD;                // (N, M, K)
    float* out_side  = out_codes + (size_t)NV * MS * KC;     // (M, N, D)

    for (int m = 0; m < MS; ++m) {
        const float* C = cb + (size_t)m * KC * DD;

        // ||res||^2 per vector (duplicated across halves, identical bits)
        float rn[4];
        #pragma unroll
        for (int v = 0; v < 4; ++v) {
            float p = rA[v][0] * rA[v][0];
            #pragma unroll
            for (int k = 1; k < 16; ++k) p += rA[v][k] * rA[v][k];
            p = bfly_add<0xB1>(p);
            p = bfly_add<0x4E>(p);
            p = bfly_add<0x141>(p);
            rn[v] = p;
        }

        float best[4]; int bi[4];
        #pragma unroll
        for (int v = 0; v < 4; ++v) { best[v] = 3.402823466e38f; bi[v] = h * 128; }

        #pragma unroll
        for (int ch = 0; ch < 3; ++ch) {
            const int cnt = CCNT[ch];

            __syncthreads();   // prior chunk's readers (and merge readers) done

            // stage paired sub-ranges, transposed chain-major:
            // slot s < cnt -> global row CB0+s ; s >= cnt -> CB1+s-cnt
            {
                const float4* g4 = (const float4*)C;
                const int nf4 = 2 * cnt * 32;
                for (int i = tid; i < nf4; i += 512) {
                    const int slot = i >> 5;
                    const int j    = i & 31;
                    const int grow = (slot < cnt) ? (CB0[ch] + slot)
                                                  : (CB1[ch] + slot - cnt);
                    float4 v = g4[grow * 32 + j];
                    const int c0 = (j & 1) * 4;
                    const int k  = j >> 1;
                    float* dst = sC + slot * RST + c0 * CST + k;
                    dst[0 * CST] = v.x;
                    dst[1 * CST] = v.y;
                    dst[2 * CST] = v.z;
                    dst[3 * CST] = v.w;
                }
            }
            // cn for both sub-ranges (bitwise-same chain code)
            if (tid < 2 * cnt) {
                const int grow = (tid < cnt) ? (CB0[ch] + tid)
                                             : (CB1[ch] + tid - cnt);
                const float* cr = C + (size_t)grow * DD;
                float p[8];
                #pragma unroll
                for (int j = 0; j < 8; ++j) { float v = cr[j]; p[j] = v * v; }
                #pragma unroll
                for (int i = 8; i < DD; i += 8) {
                    #pragma unroll
                    for (int j = 0; j < 8; ++j) { float v = cr[i + j]; p[j] += v * v; }
                }
                cn_s[tid] = ((p[0]+p[1]) + (p[2]+p[3])) + ((p[4]+p[5]) + (p[6]+p[7]));
            }
            __syncthreads();

            const int slot0 = h * cnt;
            const int gbase = h ? CB1[ch] : CB0[ch];

            #pragma unroll 2
            for (int kk = 0; kk < cnt; ++kk) {
                const float4* cr4 = (const float4*)(sC + (slot0 + kk) * RST + c * CST);
                float pa[4];
                {   // chain head is a MUL (reference chain order)
                    float4 a = cr4[0];
                    #pragma unroll
                    for (int v = 0; v < 4; ++v) {
                        pa[v]  = rA[v][0] * a.x;
                        pa[v] += rA[v][1] * a.y;
                        pa[v] += rA[v][2] * a.z;
                        pa[v] += rA[v][3] * a.w;
                    }
                }
                #pragma unroll
                for (int t = 1; t < 4; ++t) {
                    float4 a = cr4[t];
                    #pragma unroll
                    for (int v = 0; v < 4; ++v) {
                        pa[v] += rA[v][4*t    ] * a.x;
                        pa[v] += rA[v][4*t + 1] * a.y;
                        pa[v] += rA[v][4*t + 2] * a.z;
                        pa[v] += rA[v][4*t + 3] * a.w;
                    }
                }
                const float cn = cn_s[slot0 + kk];
                #pragma unroll
                for (int v = 0; v < 4; ++v) {
                    float s = pa[v];
                    s = bfly_add<0xB1>(s);
                    s = bfly_add<0x4E>(s);
                    s = bfly_add<0x141>(s);
                    float dist = (rn[v] - 2.0f * s) + cn;   // reference association
                    if (dist < best[v]) { best[v] = dist; bi[v] = gbase + kk; }
                }
            }
        }

        // merge halves through sC (free: all chunk reads barriered above)
        __syncthreads();
        {
            float* mb = sC;                      // [4][512] floats
            int*   mi = (int*)(sC + 2048);       // [4][512] ints
            #pragma unroll
            for (int v = 0; v < 4; ++v) {
                mb[v * 512 + tid] = best[v];
                mi[v * 512 + tid] = bi[v];
            }
            __syncthreads();
            const int ptid = tid ^ 256;
            #pragma unroll
            for (int v = 0; v < 4; ++v) {
                const float pb = mb[v * 512 + ptid];
                const int   pi = mi[v * 512 + ptid];
                float lob, hib; int loi, hii;
                if (h == 0) { lob = best[v]; loi = bi[v]; hib = pb;      hii = pi;    }
                else        { lob = pb;      loi = pi;    hib = best[v]; hii = bi[v]; }
                if (hib < lob) { best[v] = hib; bi[v] = hii; }
                else           { best[v] = lob; bi[v] = loi; }
            }
        }

        // rec += c ; res = x - rec (both halves, identical bits)
        #pragma unroll
        for (int v = 0; v < 4; ++v) {
            const size_t n = vbase + v;
            const float* cw = C + (size_t)bi[v] * DD + c;
            const float* xr = x + n * DD + c;
            #pragma unroll
            for (int k = 0; k < 16; ++k) {
                float cv = cw[8 * k];
                float xv = xr[8 * k];
                cA[v][k] += cv;
                rA[v][k] = xv - cA[v][k];
            }
            if (h == 0) {   // half0 stores side_output
                float* so = out_side + ((size_t)m * NV + n) * DD + c;
                #pragma unroll
                for (int k = 0; k < 16; ++k) so[8 * k] = cA[v][k];
            }
        }

        // one-hot codes: half1 only; lane c writes cols [c*32, c*32+32)
        if (h == 1) {
            #pragma unroll
            for (int v = 0; v < 4; ++v) {
                const size_t n = vbase + v;
                float* crow = out_codes + n * (size_t)(MS * KC) + (size_t)m * KC;
                const int b = bi[v];
                #pragma unroll
                for (int j4 = 0; j4 < 32; j4 += 4) {
                    const int j = c * 32 + j4;
                    float4 w;
                    w.x = (b == j    ) ? 1.0f : 0.0f;
                    w.y = (b == j + 1) ? 1.0f : 0.0f;
                    w.z = (b == j + 2) ? 1.0f : 0.0f;
                    w.w = (b == j + 3) ? 1.0f : 0.0f;
                    *(float4*)(crow + j) = w;
                }
            }
        }
    }

    // final recon: half0 only
    if (h == 0) {
        #pragma unroll
        for (int v = 0; v < 4; ++v) {
            float* ro = out_recon + (vbase + v) * DD + c;
            #pragma unroll
            for (int k = 0; k < 16; ++k) ro[8 * k] = cA[v][k];
        }
    }
}

extern "C" void kernel_launch(void* const* d_in, const int* in_sizes, int n_in,
                              void* d_out, int out_size, void* d_ws, size_t ws_size,
                              hipStream_t stream)
{
    const float* x  = (const float*)d_in[0];
    const float* cb = (const float*)d_in[1];
    float* out = (float*)d_out;
    rq_kernel<<<dim3(NV / 128), dim3(512), 0, stream>>>(x, cb, out);
}

// Round 4
// 2076.130 us; speedup vs baseline: 1.0034x; 1.0034x over previous
//
#include <hip/hip_runtime.h>

// Residual quantizer: N=65536 vectors (D=128), M=8 stages, K=256 codewords.
//
// R5->R6: R5's K-split won occupancy (44%) but spilled: VGPR=64 vs 128 live
// floats/lane (FETCH 185->966 MB = scratch reads, WRITE +0.55 GB). Cause:
// launch_bounds(512,4) was treated as 4 BLOCKS/CU (32 waves/CU -> 64-VGPR
// cap). Fix (a): launch_bounds(512,2) -> cap >=128 under either reading.
// Fix (b): halve live state so 4 waves/SIMD (<=128 VGPR, HW constraint) is
// legitimately reachable: rec (cA) is only touched in the update phase and
// equals side_output[m] bit-for-bit, so it round-trips through out_side:
//   rec_new = side[m-1] + c   (stage 0: 0.0f + c, same as cA=0; cA+=cv)
//   res     = x - rec_new
//   half0 writes side[m] (and recon at m=7)
// fp32 store/load is bit-exact; side[m-1] visibility within the block is
// guaranteed by the interleaved __syncthreads (workgroup memory fence,
// same CU). Per-lane state: rA[4][16] = 64 floats -> ~100 VGPRs, no spill.
//
// Numerics (absmax must stay 0.0): every FP sequence is byte-for-byte R5's.
// Chain c (mul + 15 sequential fma over elements 8k+c) whole in lane c&7.
// Combine: dpp quad xor1 (0xB1), xor2 (0x4E), half mirror (0x141) replicates
// ((p0+p1)+(p2+p3))+((p4+p5)+(p6+p7)) bitwise in all 8 lanes. dist =
// (rn - 2*dot) + cn, strict <. Merge rule: (hi < lo) ? hi : lo keeps
// first-min-wins (half0 indices smaller; ties pick lo).

constexpr int NV = 65536;
constexpr int DD = 128;
constexpr int MS = 8;
constexpr int KC = 256;
constexpr int CH = 112;       // LDS row slots per chunk (56+56 or 16+16)
constexpr int CST = 20;       // chain stride in dwords (16B-aligned, conflict-free)
constexpr int RST = 8 * CST;  // row stride in dwords = 160 (640 B)

// paired chunk tables: half0 rows [CB0, CB0+CNT), half1 rows [CB1, CB1+CNT)
constexpr int CB0[3]  = {0, 56, 112};
constexpr int CB1[3]  = {128, 184, 240};
constexpr int CCNT[3] = {56, 56, 16};

template<int CTRL>
__device__ __forceinline__ float bfly_add(float v) {
    // v + dpp<CTRL>(v); 0xB1 = quad xor1, 0x4E = quad xor2, 0x141 = row_half_mirror
    int p = __builtin_amdgcn_update_dpp(__float_as_int(v), __float_as_int(v),
                                        CTRL, 0xF, 0xF, true);
    return v + __int_as_float(p);
}

__global__ __launch_bounds__(512, 2)
void rq_kernel(const float* __restrict__ x,
               const float* __restrict__ cb,
               float* __restrict__ out)
{
    const int tid = threadIdx.x;
    const int h   = tid >> 8;                 // codebook half (wave-uniform)
    const int c   = tid & 7;                  // chain owned (elements 8k+c)
    const int grp = (tid >> 3) & 31;          // vector group (0..31)
    const size_t vbase = (size_t)blockIdx.x * 128 + (size_t)grp * 4;

    __shared__ __align__(16) float sC[CH * RST];   // 71680 B, chain-major+pad
    __shared__ float cn_s[CH];                     // 448 B

    // Per-lane state: chain c of 4 vectors' residuals ONLY (rec lives in
    // out_side between stages).
    float rA[4][16];

    #pragma unroll
    for (int v = 0; v < 4; ++v) {
        const float* xr = x + (vbase + v) * DD + c;
        #pragma unroll
        for (int k = 0; k < 16; ++k) rA[v][k] = xr[8 * k];
    }

    float* out_recon = out;                                  // (N, D)
    float* out_codes = out + (size_t)NV * DD;                // (N, M, K)
    float* out_side  = out_codes + (size_t)NV * MS * KC;     // (M, N, D)

    for (int m = 0; m < MS; ++m) {
        const float* C = cb + (size_t)m * KC * DD;

        // ||res||^2 per vector (duplicated across halves, identical bits)
        float rn[4];
        #pragma unroll
        for (int v = 0; v < 4; ++v) {
            float p = rA[v][0] * rA[v][0];
            #pragma unroll
            for (int k = 1; k < 16; ++k) p += rA[v][k] * rA[v][k];
            p = bfly_add<0xB1>(p);
            p = bfly_add<0x4E>(p);
            p = bfly_add<0x141>(p);
            rn[v] = p;
        }

        float best[4]; int bi[4];
        #pragma unroll
        for (int v = 0; v < 4; ++v) { best[v] = 3.402823466e38f; bi[v] = h * 128; }

        #pragma unroll
        for (int ch = 0; ch < 3; ++ch) {
            const int cnt = CCNT[ch];

            __syncthreads();   // prior chunk's readers (and merge readers) done

            // stage paired sub-ranges, transposed chain-major:
            // slot s < cnt -> global row CB0+s ; s >= cnt -> CB1+s-cnt
            {
                const float4* g4 = (const float4*)C;
                const int nf4 = 2 * cnt * 32;
                for (int i = tid; i < nf4; i += 512) {
                    const int slot = i >> 5;
                    const int j    = i & 31;
                    const int grow = (slot < cnt) ? (CB0[ch] + slot)
                                                  : (CB1[ch] + slot - cnt);
                    float4 v = g4[grow * 32 + j];
                    const int c0 = (j & 1) * 4;
                    const int k  = j >> 1;
                    float* dst = sC + slot * RST + c0 * CST + k;
                    dst[0 * CST] = v.x;
                    dst[1 * CST] = v.y;
                    dst[2 * CST] = v.z;
                    dst[3 * CST] = v.w;
                }
            }
            // cn for both sub-ranges (bitwise-same chain code)
            if (tid < 2 * cnt) {
                const int grow = (tid < cnt) ? (CB0[ch] + tid)
                                             : (CB1[ch] + tid - cnt);
                const float* cr = C + (size_t)grow * DD;
                float p[8];
                #pragma unroll
                for (int j = 0; j < 8; ++j) { float v = cr[j]; p[j] = v * v; }
                #pragma unroll
                for (int i = 8; i < DD; i += 8) {
                    #pragma unroll
                    for (int j = 0; j < 8; ++j) { float v = cr[i + j]; p[j] += v * v; }
                }
                cn_s[tid] = ((p[0]+p[1]) + (p[2]+p[3])) + ((p[4]+p[5]) + (p[6]+p[7]));
            }
            __syncthreads();

            const int slot0 = h * cnt;
            const int gbase = h ? CB1[ch] : CB0[ch];

            #pragma unroll 2
            for (int kk = 0; kk < cnt; ++kk) {
                const float4* cr4 = (const float4*)(sC + (slot0 + kk) * RST + c * CST);
                float pa[4];
                {   // chain head is a MUL (reference chain order)
                    float4 a = cr4[0];
                    #pragma unroll
                    for (int v = 0; v < 4; ++v) {
                        pa[v]  = rA[v][0] * a.x;
                        pa[v] += rA[v][1] * a.y;
                        pa[v] += rA[v][2] * a.z;
                        pa[v] += rA[v][3] * a.w;
                    }
                }
                #pragma unroll
                for (int t = 1; t < 4; ++t) {
                    float4 a = cr4[t];
                    #pragma unroll
                    for (int v = 0; v < 4; ++v) {
                        pa[v] += rA[v][4*t    ] * a.x;
                        pa[v] += rA[v][4*t + 1] * a.y;
                        pa[v] += rA[v][4*t + 2] * a.z;
                        pa[v] += rA[v][4*t + 3] * a.w;
                    }
                }
                const float cn = cn_s[slot0 + kk];
                #pragma unroll
                for (int v = 0; v < 4; ++v) {
                    float s = pa[v];
                    s = bfly_add<0xB1>(s);
                    s = bfly_add<0x4E>(s);
                    s = bfly_add<0x141>(s);
                    float dist = (rn[v] - 2.0f * s) + cn;   // reference association
                    if (dist < best[v]) { best[v] = dist; bi[v] = gbase + kk; }
                }
            }
        }

        // merge halves through sC (all chunk readers barriered above)
        __syncthreads();
        {
            float* mb = sC;                      // [4][512] floats
            int*   mi = (int*)(sC + 2048);       // [4][512] ints
            #pragma unroll
            for (int v = 0; v < 4; ++v) {
                mb[v * 512 + tid] = best[v];
                mi[v * 512 + tid] = bi[v];
            }
            __syncthreads();
            const int ptid = tid ^ 256;
            #pragma unroll
            for (int v = 0; v < 4; ++v) {
                const float pb = mb[v * 512 + ptid];
                const int   pi = mi[v * 512 + ptid];
                float lob, hib; int loi, hii;
                if (h == 0) { lob = best[v]; loi = bi[v]; hib = pb;      hii = pi;    }
                else        { lob = pb;      loi = pi;    hib = best[v]; hii = bi[v]; }
                if (hib < lob) { best[v] = hib; bi[v] = hii; }
                else           { best[v] = lob; bi[v] = loi; }
            }
        }

        // update: rec_new = side[m-1] + c (stage0: 0.0f + c); res = x - rec_new.
        // half0 stores side[m] (+ recon at last stage). Bitwise identical to
        // the register-carried cA += cv; rA = xv - cA sequence.
        const int mp = (m > 0) ? (m - 1) : 0;
        #pragma unroll
        for (int v = 0; v < 4; ++v) {
            const size_t n = vbase + v;
            const float* cw = C + (size_t)bi[v] * DD + c;
            const float* xr = x + n * DD + c;
            const float* sp = out_side + ((size_t)mp * NV + n) * DD + c;
            float* so = out_side + ((size_t)m  * NV + n) * DD + c;
            float* ro = out_recon + n * DD + c;
            #pragma unroll
            for (int k = 0; k < 16; ++k) {
                const float rp = (m > 0) ? sp[8 * k] : 0.0f;
                const float rec = rp + cw[8 * k];
                rA[v][k] = xr[8 * k] - rec;
                if (h == 0) {
                    so[8 * k] = rec;
                    if (m == MS - 1) ro[8 * k] = rec;
                }
            }
        }

        // one-hot codes: half1 only; lane c writes cols [c*32, c*32+32)
        if (h == 1) {
            #pragma unroll
            for (int v = 0; v < 4; ++v) {
                const size_t n = vbase + v;
                float* crow = out_codes + n * (size_t)(MS * KC) + (size_t)m * KC;
                const int b = bi[v];
                #pragma unroll
                for (int j4 = 0; j4 < 32; j4 += 4) {
                    const int j = c * 32 + j4;
                    float4 w;
                    w.x = (b == j    ) ? 1.0f : 0.0f;
                    w.y = (b == j + 1) ? 1.0f : 0.0f;
                    w.z = (b == j + 2) ? 1.0f : 0.0f;
                    w.w = (b == j + 3) ? 1.0f : 0.0f;
                    *(float4*)(crow + j) = w;
                }
            }
        }
    }
}

extern "C" void kernel_launch(void* const* d_in, const int* in_sizes, int n_in,
                              void* d_out, int out_size, void* d_ws, size_t ws_size,
                              hipStream_t stream)
{
    const float* x  = (const float*)d_in[0];
    const float* cb = (const float*)d_in[1];
    float* out = (float*)d_out;
    rq_kernel<<<dim3(NV / 128), dim3(512), 0, stream>>>(x, cb, out);
}